// Round 8
// baseline (349.191 us; speedup 1.0000x reference)
//
#include <hip/hip_runtime.h>
#include <cstdint>

// ---------------------------------------------------------------------------
// VAE attention block: GN -> QKV 1x1 conv -> softmax(QK^T) V -> proj + x
// B=4, H=W=64 (N=4096 pixels/batch), C=512, GROUPS=32
// R8: - gemm_f8 core REVERTED to R6 config (BK=128B, 34KB LDS, dual-16B v8i
//       reads): R7's BK=256/32B-read variant lost occupancy (28->20) and
//       added bank conflicts (4.7e6->13.1e6) -> scores 78->96 us
//     - PV re-tiled 128x64 (grid 1024, LDS 24KB): 2x resident blocks for the
//       32-iter K-loop (latency hiding)
//     - qkv now fp8 MX MFMA: h stored fp8 by gn_apply; weights fp8 with x16
//       pre-scale (avoids e4m3 subnormals; epilogue applies 1/16)
//     - gn_stats + weight-cast merged into one prep launch
//     - softmax divide stays deferred to proj (commutes through linear conv)
// ---------------------------------------------------------------------------

typedef __bf16 bf16_t;
typedef bf16_t bf16x8 __attribute__((ext_vector_type(8)));
typedef float floatx4 __attribute__((ext_vector_type(4)));
typedef int v8i __attribute__((ext_vector_type(8)));

__device__ __forceinline__ uint16_t f2b(float f) {
    uint32_t u = __builtin_bit_cast(uint32_t, f);
    u += 0x7fffu + ((u >> 16) & 1u);
    return (uint16_t)(u >> 16);
}
__device__ __forceinline__ float b2f(uint16_t h) {
    uint32_t u = ((uint32_t)h) << 16;
    return __builtin_bit_cast(float, u);
}
// pack 4 floats -> 4 fp8 e4m3 bytes
__device__ __forceinline__ unsigned pk_fp8x4(float a, float b, float c, float d) {
    int w = __builtin_amdgcn_cvt_pk_fp8_f32(a, b, 0, false);
    w = __builtin_amdgcn_cvt_pk_fp8_f32(c, d, w, true);
    return (unsigned)w;
}
__device__ __forceinline__ uint8_t to_fp8(float a) {
    return (uint8_t)(__builtin_amdgcn_cvt_pk_fp8_f32(a, a, 0, false) & 0xff);
}

__device__ __forceinline__ void lds_copy16(void* lds, const void* glob) {
    __builtin_amdgcn_global_load_lds(
        (__attribute__((address_space(1))) void*)(void*)glob,
        (__attribute__((address_space(3))) void*)lds,
        16, 0, 0);
}

// ---------------------------------------------------------------------------
// prep: blocks 0..127 -> GroupNorm stats (+ zero lrow); blocks 128..383 ->
// weight cast/transpose: wq/wk/wv -> fp8(16*w)^T, wp -> bf16 w^T.
// ---------------------------------------------------------------------------
__global__ __launch_bounds__(256) void prep(const float* __restrict__ x,
                                            float* __restrict__ stats,
                                            float* __restrict__ lrow,
                                            const float* __restrict__ w0,
                                            const float* __restrict__ w1,
                                            const float* __restrict__ w2,
                                            const float* __restrict__ w3,
                                            uint8_t* __restrict__ w8,
                                            uint16_t* __restrict__ wp16) {
    __shared__ float tf[64][65];
    __shared__ float rs[4], rq[4];
    const int tid = threadIdx.x;
    const int blk = blockIdx.x;
    if (blk < 128) {
        const int bg = blk;
        if (tid < 128) lrow[bg * 128 + tid] = 0.f;   // 128*128 = 16384 rows
        const int b = bg >> 5, g = bg & 31;
        const float* base = x + (long)b * (4096L * 512) + g * 16;
        float s = 0.f, sq = 0.f;
        #pragma unroll 8
        for (int i = 0; i < 64; i++) {
            int idx4 = tid + i * 256;
            int pixel = idx4 >> 2, c4 = idx4 & 3;
            const float4 v = *(const float4*)(base + (long)pixel * 512 + c4 * 4);
            s += v.x + v.y + v.z + v.w;
            sq += v.x * v.x + v.y * v.y + v.z * v.z + v.w * v.w;
        }
        #pragma unroll
        for (int off = 32; off > 0; off >>= 1) {
            s += __shfl_down(s, off);
            sq += __shfl_down(sq, off);
        }
        const int lane = tid & 63, w = tid >> 6;
        if (lane == 0) { rs[w] = s; rq[w] = sq; }
        __syncthreads();
        if (tid == 0) {
            float S = rs[0] + rs[1] + rs[2] + rs[3];
            float Q = rq[0] + rq[1] + rq[2] + rq[3];
            float mean = S * (1.f / 65536.f);
            float var = Q * (1.f / 65536.f) - mean * mean;
            stats[bg * 2 + 0] = mean;
            stats[bg * 2 + 1] = rsqrtf(var + 1e-5f);
        }
    } else {
        const int t = blk - 128;            // 0..255
        const int z = t >> 6;               // which weight
        const int tt = t & 63;
        const int nb = (tt & 7) * 64, kb = (tt >> 3) * 64;
        const float* ws[4] = {w0, w1, w2, w3};
        const float* w = ws[z];
        const int lc = tid & 63, lg = tid >> 6;
        #pragma unroll
        for (int i = 0; i < 16; i++) {
            int r = lg * 16 + i;
            tf[lc][r] = w[(long)(kb + r) * 512 + nb + lc];   // tf[n_loc][k_loc]
        }
        __syncthreads();
        if (z < 3) {
            uint8_t* o = w8 + (long)z * 512 * 512;
            #pragma unroll
            for (int i = 0; i < 16; i++) {
                int r = lg * 16 + i;
                o[(long)(nb + r) * 512 + kb + lc] = to_fp8(16.f * tf[r][lc]);
            }
        } else {
            #pragma unroll
            for (int i = 0; i < 16; i++) {
                int r = lg * 16 + i;
                wp16[(long)(nb + r) * 512 + kb + lc] = f2b(tf[r][lc]);
            }
        }
    }
}

// ---------------------------------------------------------------------------
// GroupNorm apply: h_fp8 = fp8((x-mean)*rstd*gamma + beta).  4 elems/thread.
// ---------------------------------------------------------------------------
__global__ __launch_bounds__(256) void gn_apply(const float* __restrict__ x,
                                                const float* __restrict__ stats,
                                                const float* __restrict__ gamma,
                                                const float* __restrict__ beta,
                                                uint8_t* __restrict__ h) {
    const long idx4 = (long)blockIdx.x * 256 + threadIdx.x;   // 0..2097151
    const long e0 = idx4 * 4;
    const int c = (int)(e0 & 511);
    const int b = (int)(e0 >> 21);                            // 4096*512 = 2^21
    const float2 st = ((const float2*)stats)[b * 32 + (c >> 4)];
    const float4 v = ((const float4*)x)[idx4];
    const float4 gm = ((const float4*)gamma)[c >> 2];
    const float4 bt = ((const float4*)beta)[c >> 2];
    ((unsigned*)h)[idx4] = pk_fp8x4((v.x - st.x) * st.y * gm.x + bt.x,
                                    (v.y - st.x) * st.y * gm.y + bt.y,
                                    (v.z - st.x) * st.y * gm.z + bt.z,
                                    (v.w - st.x) * st.y * gm.w + bt.w);
}

// ---------------------------------------------------------------------------
// Fused QKV GEMM (fp8 MX MFMA): [16384,512] x [1536,512]^T.  Grid (12, 128).
// A = h fp8, B = fp8(16*w)^T -> epilogue scales by 1/16 and adds bias.
// Outputs fp8: cols 0-511 -> q, 512-1023 -> k, 1024-1535 -> v stored
// TRANSPOSED (vt[b][ch][pix]).
// ---------------------------------------------------------------------------
__global__ __launch_bounds__(256) void qkv_f8(const uint8_t* __restrict__ h,
                                              const uint8_t* __restrict__ w8,
                                              const float* __restrict__ bq,
                                              const float* __restrict__ bk,
                                              const float* __restrict__ bv,
                                              uint8_t* __restrict__ q,
                                              uint8_t* __restrict__ k,
                                              uint8_t* __restrict__ vt) {
    __shared__ __align__(16) uint8_t smem8[34816];
    uint8_t* sA = smem8;                 // 128 x 128B
    uint8_t* sB = smem8 + 16384;         // 128 x 128B
    uint16_t* tile = (uint16_t*)smem8;   // epilogue bf16 reuse, stride 136

    const int tid = threadIdx.x;
    const long m0 = (long)blockIdx.y * 128;
    const int n0 = blockIdx.x * 128;

    const int lane = tid & 63;
    const int wave = tid >> 6;
    const int wm = (wave & 1) * 64;
    const int wn = (wave >> 1) * 64;
    const int fr = lane & 15;
    const int quad = lane >> 4;
    const int sw = fr & 7;

    floatx4 acc[4][4];
    #pragma unroll
    for (int i = 0; i < 4; i++)
        #pragma unroll
        for (int j = 0; j < 4; j++) acc[i][j] = (floatx4){0.f, 0.f, 0.f, 0.f};

    const int p0c = (2 * quad) ^ sw;
    const int p1c = (2 * quad + 1) ^ sw;

    for (int kt = 0; kt < 512; kt += 128) {
        __syncthreads();
        #pragma unroll
        for (int i = 0; i < 4; i++) {
            const int c = i * 256 + tid;           // 1024 16B-chunks per matrix
            const int row = c >> 3;
            const int gj = (c & 7) ^ (row & 7);
            lds_copy16(&sA[c * 16], h + (m0 + row) * 512L + kt + gj * 16);
            lds_copy16(&sB[c * 16], w8 + (n0 + row) * 512L + kt + gj * 16);
        }
        __syncthreads();
        v8i af[4], bf[4];
        #pragma unroll
        for (int mi = 0; mi < 4; mi++) {
            const int row = wm + mi * 16 + fr;
            const uint4 lo = *(const uint4*)&sA[row * 128 + p0c * 16];
            const uint4 hi = *(const uint4*)&sA[row * 128 + p1c * 16];
            af[mi] = (v8i){(int)lo.x, (int)lo.y, (int)lo.z, (int)lo.w,
                           (int)hi.x, (int)hi.y, (int)hi.z, (int)hi.w};
        }
        #pragma unroll
        for (int ni = 0; ni < 4; ni++) {
            const int row = wn + ni * 16 + fr;
            const uint4 lo = *(const uint4*)&sB[row * 128 + p0c * 16];
            const uint4 hi = *(const uint4*)&sB[row * 128 + p1c * 16];
            bf[ni] = (v8i){(int)lo.x, (int)lo.y, (int)lo.z, (int)lo.w,
                           (int)hi.x, (int)hi.y, (int)hi.z, (int)hi.w};
        }
        #pragma unroll
        for (int mi = 0; mi < 4; mi++)
            #pragma unroll
            for (int ni = 0; ni < 4; ni++)
                acc[mi][ni] = __builtin_amdgcn_mfma_scale_f32_16x16x128_f8f6f4(
                    af[mi], bf[ni], acc[mi][ni], 0, 0,
                    0, 0x7f7f7f7fu, 0, 0x7f7f7f7fu);
    }

    const int w = n0 >> 9;          // 0=q, 1=k, 2=v(T)
    const int nc = n0 & 511;
    const float* bias = (w == 0) ? bq : (w == 1) ? bk : bv;
    __syncthreads();
    if (w < 2) {
        #pragma unroll
        for (int ni = 0; ni < 4; ni++) {
            const int col_l = wn + ni * 16 + fr;
            const float bb = bias[nc + col_l];
            #pragma unroll
            for (int mi = 0; mi < 4; mi++) {
                #pragma unroll
                for (int r = 0; r < 4; r++) {
                    const int row_l = wm + mi * 16 + quad * 4 + r;
                    tile[row_l * 136 + col_l] = f2b(acc[mi][ni][r] * 0.0625f + bb);
                }
            }
        }
        __syncthreads();
        uint8_t* out = (w == 0) ? q : k;
        #pragma unroll
        for (int it = 0; it < 8; it++) {
            const int row_l = it * 16 + (tid >> 4);
            const int c0 = (tid & 15) * 8;
            const uint4 d = *(const uint4*)&tile[row_l * 136 + c0];
            const uint16_t* e = (const uint16_t*)&d;
            uint2 o;
            o.x = pk_fp8x4(b2f(e[0]), b2f(e[1]), b2f(e[2]), b2f(e[3]));
            o.y = pk_fp8x4(b2f(e[4]), b2f(e[5]), b2f(e[6]), b2f(e[7]));
            *(uint2*)&out[(m0 + row_l) * 512 + nc + c0] = o;
        }
    } else {
        // transposed fp8 repack: s8[ch][pix], byte stride 144 (16B-aligned)
        uint8_t* s8 = smem8;
        #pragma unroll
        for (int ni = 0; ni < 4; ni++) {
            const int ch_l = wn + ni * 16 + fr;
            const float bb = bias[nc + ch_l];
            #pragma unroll
            for (int mi = 0; mi < 4; mi++) {
                const int pix0 = wm + mi * 16 + quad * 4;
                *(unsigned*)&s8[ch_l * 144 + pix0] =
                    pk_fp8x4(acc[mi][ni][0] * 0.0625f + bb,
                             acc[mi][ni][1] * 0.0625f + bb,
                             acc[mi][ni][2] * 0.0625f + bb,
                             acc[mi][ni][3] * 0.0625f + bb);
            }
        }
        __syncthreads();
        const long b = m0 >> 12;
        const int pixb = (int)(m0 & 4095);
        uint8_t* vtb = vt + b * (512L * 4096);
        #pragma unroll
        for (int it = 0; it < 4; it++) {
            const int ch_l = it * 32 + (tid >> 3);
            const int p0 = (tid & 7) * 16;
            *(uint4*)&vtb[(long)(nc + ch_l) * 4096 + pixb + p0] =
                *(const uint4*)&s8[ch_l * 144 + p0];
        }
    }
}

// ---------------------------------------------------------------------------
// Scores GEMM (fp8 MX MFMA, R6 core): p = exp2(scale * q.k^T) -> fp8 sc +
// fp32 row-sum atomics.  128x128 tile, BK=128B, grid (32, 32, 4).
// ---------------------------------------------------------------------------
__global__ __launch_bounds__(256) void scores_f8(const uint8_t* __restrict__ A,
                                                 const uint8_t* __restrict__ B,
                                                 uint8_t* __restrict__ Cout,
                                                 float* __restrict__ lrow,
                                                 float scale) {
    __shared__ __align__(16) uint8_t smem8[34816];
    uint8_t* sA = smem8;
    uint8_t* sB = smem8 + 16384;
    uint16_t* tile = (uint16_t*)smem8;

    const int tid = threadIdx.x;
    const int bz = blockIdx.z;
    const long m0 = (long)blockIdx.y * 128;
    const long n0 = (long)blockIdx.x * 128;
    const uint8_t* Ab = A + (long)bz * (4096L * 512);
    const uint8_t* Bb = B + (long)bz * (4096L * 512);

    const int lane = tid & 63;
    const int wave = tid >> 6;
    const int wm = (wave & 1) * 64;
    const int wn = (wave >> 1) * 64;
    const int fr = lane & 15;
    const int quad = lane >> 4;
    const int sw = fr & 7;

    floatx4 acc[4][4];
    #pragma unroll
    for (int i = 0; i < 4; i++)
        #pragma unroll
        for (int j = 0; j < 4; j++) acc[i][j] = (floatx4){0.f, 0.f, 0.f, 0.f};

    const int p0c = (2 * quad) ^ sw;
    const int p1c = (2 * quad + 1) ^ sw;

    for (int kt = 0; kt < 512; kt += 128) {
        __syncthreads();
        #pragma unroll
        for (int i = 0; i < 4; i++) {
            const int c = i * 256 + tid;
            const int row = c >> 3;
            const int gj = (c & 7) ^ (row & 7);
            lds_copy16(&sA[c * 16], Ab + (m0 + row) * 512L + kt + gj * 16);
            lds_copy16(&sB[c * 16], Bb + (n0 + row) * 512L + kt + gj * 16);
        }
        __syncthreads();
        v8i af[4], bf[4];
        #pragma unroll
        for (int mi = 0; mi < 4; mi++) {
            const int row = wm + mi * 16 + fr;
            const uint4 lo = *(const uint4*)&sA[row * 128 + p0c * 16];
            const uint4 hi = *(const uint4*)&sA[row * 128 + p1c * 16];
            af[mi] = (v8i){(int)lo.x, (int)lo.y, (int)lo.z, (int)lo.w,
                           (int)hi.x, (int)hi.y, (int)hi.z, (int)hi.w};
        }
        #pragma unroll
        for (int ni = 0; ni < 4; ni++) {
            const int row = wn + ni * 16 + fr;
            const uint4 lo = *(const uint4*)&sB[row * 128 + p0c * 16];
            const uint4 hi = *(const uint4*)&sB[row * 128 + p1c * 16];
            bf[ni] = (v8i){(int)lo.x, (int)lo.y, (int)lo.z, (int)lo.w,
                           (int)hi.x, (int)hi.y, (int)hi.z, (int)hi.w};
        }
        #pragma unroll
        for (int mi = 0; mi < 4; mi++)
            #pragma unroll
            for (int ni = 0; ni < 4; ni++)
                acc[mi][ni] = __builtin_amdgcn_mfma_scale_f32_16x16x128_f8f6f4(
                    af[mi], bf[ni], acc[mi][ni], 0, 0,
                    0, 0x7f7f7f7fu, 0, 0x7f7f7f7fu);
    }

    __syncthreads();
    // p = exp2(acc*scale) -> truncated bf16 tile (p tolerates 2^-8 rel)
    #pragma unroll
    for (int ni = 0; ni < 4; ni++) {
        const int col_l = wn + ni * 16 + fr;
        #pragma unroll
        for (int mi = 0; mi < 4; mi++) {
            #pragma unroll
            for (int r = 0; r < 4; r++) {
                const int row_l = wm + mi * 16 + quad * 4 + r;
                const float v = exp2f(acc[mi][ni][r] * scale);
                tile[row_l * 136 + col_l] =
                    (uint16_t)(__builtin_bit_cast(uint32_t, v) >> 16);
            }
        }
    }
    __syncthreads();
    uint8_t* Cb = Cout + (long)bz * (4096L * 4096);
    float* lb = lrow + (long)bz * 4096;
    #pragma unroll
    for (int it = 0; it < 8; it++) {
        const int row_l = it * 16 + (tid >> 4);
        const int c0 = (tid & 15) * 8;
        const uint4 d = *(const uint4*)&tile[row_l * 136 + c0];
        const uint16_t* e = (const uint16_t*)&d;
        float f[8];
        float ps = 0.f;
        #pragma unroll
        for (int j = 0; j < 8; j++) { f[j] = b2f(e[j]); ps += f[j]; }
        uint2 o;
        o.x = pk_fp8x4(f[0], f[1], f[2], f[3]);
        o.y = pk_fp8x4(f[4], f[5], f[6], f[7]);
        *(uint2*)&Cb[(m0 + row_l) * 4096 + n0 + c0] = o;
        #pragma unroll
        for (int off = 1; off < 16; off <<= 1) ps += __shfl_xor(ps, off);
        if ((tid & 15) == 0) atomicAdd(&lb[m0 + row_l], ps);
    }
}

// ---------------------------------------------------------------------------
// PV GEMM (fp8 MX MFMA): ao_un[b] = p[b] @ v[b]  (divide deferred to proj).
// 128x64 tile (grid (8, 32, 4) = 1024 blocks), BK=128B, LDS 24KB -> high
// occupancy for the 32-iteration K=4096 loop.
// ---------------------------------------------------------------------------
__global__ __launch_bounds__(256) void pv_f8(const uint8_t* __restrict__ A,
                                             const uint8_t* __restrict__ B,
                                             uint16_t* __restrict__ ao) {
    __shared__ __align__(16) uint8_t smem8[24576];
    uint8_t* sA = smem8;                 // 128 x 128B
    uint8_t* sB = smem8 + 16384;         // 64 x 128B
    uint16_t* tile = (uint16_t*)smem8;   // epilogue bf16 reuse, stride 72

    const int tid = threadIdx.x;
    const int bz = blockIdx.z;
    const long m0 = (long)blockIdx.y * 128;
    const int n0 = blockIdx.x * 64;
    const uint8_t* Ab = A + (long)bz * (4096L * 4096);
    const uint8_t* Bb = B + (long)bz * (512L * 4096);

    const int lane = tid & 63;
    const int wave = tid >> 6;
    const int wm = (wave & 1) * 64;
    const int wn = (wave >> 1) * 32;
    const int fr = lane & 15;
    const int quad = lane >> 4;
    const int sw = fr & 7;

    floatx4 acc[4][2];
    #pragma unroll
    for (int i = 0; i < 4; i++)
        #pragma unroll
        for (int j = 0; j < 2; j++) acc[i][j] = (floatx4){0.f, 0.f, 0.f, 0.f};

    const int p0c = (2 * quad) ^ sw;
    const int p1c = (2 * quad + 1) ^ sw;

    for (int kt = 0; kt < 4096; kt += 128) {
        __syncthreads();
        #pragma unroll
        for (int i = 0; i < 4; i++) {
            const int c = i * 256 + tid;           // A: 1024 chunks
            const int row = c >> 3;
            const int gj = (c & 7) ^ (row & 7);
            lds_copy16(&sA[c * 16], Ab + (m0 + row) * 4096L + kt + gj * 16);
        }
        #pragma unroll
        for (int i = 0; i < 2; i++) {
            const int c = i * 256 + tid;           // B: 512 chunks
            const int row = c >> 3;
            const int gj = (c & 7) ^ (row & 7);
            lds_copy16(&sB[c * 16], Bb + (long)(n0 + row) * 4096 + kt + gj * 16);
        }
        __syncthreads();
        v8i af[4], bf[2];
        #pragma unroll
        for (int mi = 0; mi < 4; mi++) {
            const int row = wm + mi * 16 + fr;
            const uint4 lo = *(const uint4*)&sA[row * 128 + p0c * 16];
            const uint4 hi = *(const uint4*)&sA[row * 128 + p1c * 16];
            af[mi] = (v8i){(int)lo.x, (int)lo.y, (int)lo.z, (int)lo.w,
                           (int)hi.x, (int)hi.y, (int)hi.z, (int)hi.w};
        }
        #pragma unroll
        for (int ni = 0; ni < 2; ni++) {
            const int row = wn + ni * 16 + fr;
            const uint4 lo = *(const uint4*)&sB[row * 128 + p0c * 16];
            const uint4 hi = *(const uint4*)&sB[row * 128 + p1c * 16];
            bf[ni] = (v8i){(int)lo.x, (int)lo.y, (int)lo.z, (int)lo.w,
                           (int)hi.x, (int)hi.y, (int)hi.z, (int)hi.w};
        }
        #pragma unroll
        for (int mi = 0; mi < 4; mi++)
            #pragma unroll
            for (int ni = 0; ni < 2; ni++)
                acc[mi][ni] = __builtin_amdgcn_mfma_scale_f32_16x16x128_f8f6f4(
                    af[mi], bf[ni], acc[mi][ni], 0, 0,
                    0, 0x7f7f7f7fu, 0, 0x7f7f7f7fu);
    }

    __syncthreads();
    #pragma unroll
    for (int ni = 0; ni < 2; ni++) {
        const int col_l = wn + ni * 16 + fr;
        #pragma unroll
        for (int mi = 0; mi < 4; mi++) {
            #pragma unroll
            for (int r = 0; r < 4; r++) {
                const int row_l = wm + mi * 16 + quad * 4 + r;
                tile[row_l * 72 + col_l] = f2b(acc[mi][ni][r]);
            }
        }
    }
    __syncthreads();
    uint16_t* aob = ao + (long)bz * (4096L * 512);
    #pragma unroll
    for (int it = 0; it < 4; it++) {
        const int row_l = it * 32 + (tid >> 3);
        const int c0 = (tid & 7) * 8;
        *(uint4*)&aob[(m0 + row_l) * 512 + n0 + c0] =
            *(const uint4*)&tile[row_l * 72 + c0];
    }
}

// ---------------------------------------------------------------------------
// Projection GEMM (bf16 MFMA): out[m][n] = acc[m][n]/l[m] + bp[n] + x[m][n]
// (softmax divide commutes through the per-row linear conv)
// ---------------------------------------------------------------------------
__global__ __launch_bounds__(256) void gemm_proj(const uint16_t* __restrict__ A,
                                                 const uint16_t* __restrict__ B,
                                                 float* __restrict__ Cout,
                                                 const float* __restrict__ bias,
                                                 const float* __restrict__ resid,
                                                 const float* __restrict__ lrow) {
    __shared__ __align__(16) uint16_t smem[128 * 136];
    __shared__ float lbuf[128];
    uint16_t* sA = smem;
    uint16_t* sB = smem + 8192;
    const int N = 512;

    const int tid = threadIdx.x;
    const long m0 = (long)blockIdx.y * 128;
    const long n0 = (long)blockIdx.x * 128;

    if (tid < 128) lbuf[tid] = lrow[m0 + tid];

    const int lane = tid & 63;
    const int wave = tid >> 6;
    const int wm = (wave & 1) * 64;
    const int wn = (wave >> 1) * 64;
    const int fr = lane & 15;
    const int fh = lane >> 4;
    const int sw = fr & 7;

    floatx4 acc[4][4];
    #pragma unroll
    for (int i = 0; i < 4; i++)
        #pragma unroll
        for (int j = 0; j < 4; j++) acc[i][j] = (floatx4){0.f, 0.f, 0.f, 0.f};

    for (int kt = 0; kt < 512; kt += 64) {
        __syncthreads();
        #pragma unroll
        for (int i = 0; i < 4; i++) {
            const int c = i * 256 + tid;
            const int row = c >> 3;
            const int gj = (c & 7) ^ (row & 7);
            lds_copy16(&sA[c * 8], A + (m0 + row) * 512L + kt + gj * 8);
            lds_copy16(&sB[c * 8], B + (n0 + row) * 512L + kt + gj * 8);
        }
        __syncthreads();
        #pragma unroll
        for (int kk = 0; kk < 64; kk += 32) {
            const int jx = ((fh + (kk >> 3)) ^ sw) * 8;
            bf16x8 av[4], bv[4];
            #pragma unroll
            for (int mi = 0; mi < 4; mi++)
                av[mi] = *(const bf16x8*)&sA[(wm + mi * 16 + fr) * 64 + jx];
            #pragma unroll
            for (int ni = 0; ni < 4; ni++)
                bv[ni] = *(const bf16x8*)&sB[(wn + ni * 16 + fr) * 64 + jx];
            #pragma unroll
            for (int mi = 0; mi < 4; mi++)
                #pragma unroll
                for (int ni = 0; ni < 4; ni++)
                    acc[mi][ni] = __builtin_amdgcn_mfma_f32_16x16x32_bf16(
                        av[mi], bv[ni], acc[mi][ni], 0, 0, 0);
        }
    }

    const int quad = lane >> 4;
    #pragma unroll
    for (int ni = 0; ni < 4; ni++) {
        const long col = n0 + wn + ni * 16 + fr;
        const float bv_ = bias[col];
        #pragma unroll
        for (int mi = 0; mi < 4; mi++) {
            #pragma unroll
            for (int r = 0; r < 4; r++) {
                const int rl = wm + mi * 16 + quad * 4 + r;
                const long row = m0 + rl;
                const float inv = __builtin_amdgcn_rcpf(lbuf[rl]);
                Cout[row * N + col] = acc[mi][ni][r] * inv + bv_ + resid[row * N + col];
            }
        }
    }
}

// ---------------------------------------------------------------------------
extern "C" void kernel_launch(void* const* d_in, const int* in_sizes, int n_in,
                              void* d_out, int out_size, void* d_ws, size_t ws_size,
                              hipStream_t stream) {
    const float* x  = (const float*)d_in[0];
    const float* gg = (const float*)d_in[1];
    const float* gb = (const float*)d_in[2];
    const float* wq = (const float*)d_in[3];
    const float* bq = (const float*)d_in[4];
    const float* wk = (const float*)d_in[5];
    const float* bk = (const float*)d_in[6];
    const float* wv = (const float*)d_in[7];
    const float* bv = (const float*)d_in[8];
    const float* wp = (const float*)d_in[9];
    const float* bp = (const float*)d_in[10];
    float* out = (float*)d_out;

    char* ws = (char*)d_ws;
    size_t off = 0;
    auto alloc = [&](size_t bytes) {
        char* p = ws + off;
        off += (bytes + 255) & ~(size_t)255;
        return p;
    };
    float*    stats = (float*)alloc(128 * 2 * sizeof(float));
    float*    lrow  = (float*)alloc(16384L * 4);
    uint8_t*  h8    = (uint8_t*)alloc(16384L * 512);
    uint8_t*  w8    = (uint8_t*)alloc(3L * 512 * 512);
    uint16_t* wp16  = (uint16_t*)alloc(512L * 512 * 2);
    uint8_t*  q8    = (uint8_t*)alloc(16384L * 512);
    uint8_t*  k8    = (uint8_t*)alloc(16384L * 512);
    uint8_t*  vt8   = (uint8_t*)alloc(16384L * 512);
    uint8_t*  sc8   = (uint8_t*)alloc(4L * 4096 * 4096);
    uint16_t* ao    = (uint16_t*)alloc(16384L * 512 * 2);
    if (off > ws_size) return;  // workspace too small -> fail visibly

    // stats + lrow zero + weight cast (one launch)
    prep<<<384, 256, 0, stream>>>(x, stats, lrow, wq, wk, wv, wp, w8, wp16);
    gn_apply<<<8192, 256, 0, stream>>>(x, stats, gg, gb, h8);
    // q / k / v^T (fp8) in one dispatch
    qkv_f8<<<dim3(12, 128), 256, 0, stream>>>(h8, w8, bq, bk, bv, q8, k8, vt8);
    // p[b] = exp2(scale * q[b] @ k[b]^T) as fp8, row sums into lrow
    const float qscale = 0.06375871540654937f;   // log2(e)/sqrt(512)
    scores_f8<<<dim3(32, 32, 4), 256, 0, stream>>>(q8, k8, sc8, lrow, qscale);
    // ao_un[b] = p[b] @ v[b]   (divide deferred to proj)
    pv_f8<<<dim3(8, 32, 4), 256, 0, stream>>>(sc8, vt8, ao);
    // out = x + (ao_un @ wp^T)/l + bp
    gemm_proj<<<dim3(4, 128), 256, 0, stream>>>(ao, wp16, out, bp, x, lrow);
}